// Round 8
// baseline (635.208 us; speedup 1.0000x reference)
//
#include <hip/hip_runtime.h>
#include <hip/hip_bf16.h>

// B=4,H=8,N=2048,DV=64. BH=32.
// P_d = stable argsort of v[:,d] (per bh), Q_d = inverse perm, vs_d = sorted col.
// out[r,d] = vs_d[ Q_{(d+1)%64}[r] ]
// attn[r,:] = one_hot( P_0[ Q_1[r] ] )
// ws: Q ushort[32*64*2048] (8MB) | vs float[32*64*2048] (16MB) | P0 ushort[32*2048]
// outT scratch (16MB) lives at the start of the attn region of d_out; it is
// fully consumed by out_transpose before attn_kernel overwrites the region.

#define SORT_N 2048
#define SORT_T 256
#define NBH 32
#define NDV 64
#define SLOT(i) ((i) + ((i) >> 3))   // +1 u64 pad per 8 elems: breaks 64B-stride bank aliasing

__device__ __forceinline__ void ce(unsigned long long& a, unsigned long long& b, bool up) {
  if ((a > b) == up) { unsigned long long t = a; a = b; b = t; }
}

// -------- Kernel 1: hybrid bitonic stable argsort, TWO adjacent cols/block --
// Same loop/barrier structure as the compile-proven R2 kernel; every LDS pair
// op is duplicated for col d0 (key0) and d0+1 (key1), sharing the index math.
__global__ __launch_bounds__(SORT_T) void sort_kernel(
    const float* __restrict__ v, unsigned short* __restrict__ Q,
    float* __restrict__ vs, unsigned short* __restrict__ P0) {
  const int blk  = blockIdx.x;        // bh*32 + (d0>>1)
  const int bh   = blk >> 5;
  const int d0   = (blk & 31) << 1;   // even column; col1 = d0+1 (same bh)
  const int col0 = (bh << 6) + d0;
  const float2* vrow = (const float2*)(v + (size_t)bh * SORT_N * NDV + d0);
  // element n of both columns: vrow[n*32] = (v[n][d0], v[n][d0+1])

  __shared__ unsigned long long key0[SORT_N + SORT_N / 8];  // 18 KiB padded
  __shared__ unsigned long long key1[SORT_N + SORT_N / 8];  // 18 KiB padded
  const int t = threadIdx.x;
  const int base = t * 8;            // thread owns elements [base, base+8)

  unsigned long long r0[8], r1[8];
#pragma unroll
  for (int e = 0; e < 8; ++e) {
    float2 f2 = vrow[(size_t)(base + e) * 32];
    unsigned u0 = __float_as_uint(f2.x);
    unsigned u1 = __float_as_uint(f2.y);
    u0 = (u0 & 0x80000000u) ? ~u0 : (u0 | 0x80000000u);   // order-preserving bias
    u1 = (u1 & 0x80000000u) ? ~u1 : (u1 | 0x80000000u);
    r0[e] = ((unsigned long long)u0 << 32) | (unsigned)(base + e);  // stable
    r1[e] = ((unsigned long long)u1 << 32) | (unsigned)(base + e);
  }

  // phases k=2,4,8 entirely in registers (no barriers)
#pragma unroll
  for (int e = 0; e < 8; e += 2) {
    bool up2 = ((base + e) & 2) == 0;
    ce(r0[e], r0[e + 1], up2);
    ce(r1[e], r1[e + 1], up2);
  }
#pragma unroll
  for (int e0 = 0; e0 < 8; e0 += 4) {
    bool up4 = ((base + e0) & 4) == 0;
    ce(r0[e0], r0[e0 + 2], up4); ce(r0[e0 + 1], r0[e0 + 3], up4);
    ce(r0[e0], r0[e0 + 1], up4); ce(r0[e0 + 2], r0[e0 + 3], up4);
    ce(r1[e0], r1[e0 + 2], up4); ce(r1[e0 + 1], r1[e0 + 3], up4);
    ce(r1[e0], r1[e0 + 1], up4); ce(r1[e0 + 2], r1[e0 + 3], up4);
  }
  {
    bool up8 = (base & 8) == 0;
    ce(r0[0], r0[4], up8); ce(r0[1], r0[5], up8); ce(r0[2], r0[6], up8); ce(r0[3], r0[7], up8);
    ce(r0[0], r0[2], up8); ce(r0[1], r0[3], up8); ce(r0[4], r0[6], up8); ce(r0[5], r0[7], up8);
    ce(r0[0], r0[1], up8); ce(r0[2], r0[3], up8); ce(r0[4], r0[5], up8); ce(r0[6], r0[7], up8);
    ce(r1[0], r1[4], up8); ce(r1[1], r1[5], up8); ce(r1[2], r1[6], up8); ce(r1[3], r1[7], up8);
    ce(r1[0], r1[2], up8); ce(r1[1], r1[3], up8); ce(r1[4], r1[6], up8); ce(r1[5], r1[7], up8);
    ce(r1[0], r1[1], up8); ce(r1[2], r1[3], up8); ce(r1[4], r1[5], up8); ce(r1[6], r1[7], up8);
  }
#pragma unroll
  for (int e = 0; e < 8; ++e) {
    key0[SLOT(base + e)] = r0[e];
    key1[SLOT(base + e)] = r1[e];
  }
  __syncthreads();

  for (int k = 16; k <= SORT_N; k <<= 1) {
    // LDS passes j = k/2 .. 8 : dense pair enumeration, 4 pairs/thread/column
    for (int j = k >> 1; j >= 8; j >>= 1) {
#pragma unroll
      for (int s = 0; s < 4; ++s) {
        int p = t + s * SORT_T;           // pair index 0..1023
        int low = p & (j - 1);
        int i = ((p ^ low) << 1) | low;   // lower element of pair
        bool up = (i & k) == 0;
        int si = SLOT(i), sj = SLOT(i + j);
        unsigned long long a0 = key0[si];
        unsigned long long b0 = key0[sj];
        if ((a0 > b0) == up) { key0[si] = b0; key0[sj] = a0; }
        unsigned long long a1 = key1[si];
        unsigned long long b1 = key1[sj];
        if ((a1 > b1) == up) { key1[si] = b1; key1[sj] = a1; }
      }
      __syncthreads();
    }
    // j = 4,2,1 in registers (direction uniform per chunk since k >= 16)
#pragma unroll
    for (int e = 0; e < 8; ++e) { r0[e] = key0[SLOT(base + e)]; r1[e] = key1[SLOT(base + e)]; }
    bool up = (base & k) == 0;
    ce(r0[0], r0[4], up); ce(r0[1], r0[5], up); ce(r0[2], r0[6], up); ce(r0[3], r0[7], up);
    ce(r0[0], r0[2], up); ce(r0[1], r0[3], up); ce(r0[4], r0[6], up); ce(r0[5], r0[7], up);
    ce(r0[0], r0[1], up); ce(r0[2], r0[3], up); ce(r0[4], r0[5], up); ce(r0[6], r0[7], up);
    ce(r1[0], r1[4], up); ce(r1[1], r1[5], up); ce(r1[2], r1[6], up); ce(r1[3], r1[7], up);
    ce(r1[0], r1[2], up); ce(r1[1], r1[3], up); ce(r1[4], r1[6], up); ce(r1[5], r1[7], up);
    ce(r1[0], r1[1], up); ce(r1[2], r1[3], up); ce(r1[4], r1[5], up); ce(r1[6], r1[7], up);
#pragma unroll
    for (int e = 0; e < 8; ++e) { key0[SLOT(base + e)] = r0[e]; key1[SLOT(base + e)] = r1[e]; }
    __syncthreads();
  }

  unsigned short* Qcol0 = Q + (size_t)col0 * SORT_N;
  unsigned short* Qcol1 = Qcol0 + SORT_N;
  float* vscol0 = vs + (size_t)col0 * SORT_N;
  float* vscol1 = vscol0 + SORT_N;
#pragma unroll
  for (int s = 0; s < 8; ++s) {
    int rr = t + s * SORT_T;
    unsigned long long kk0 = key0[SLOT(rr)];
    unsigned long long kk1 = key1[SLOT(rr)];
    int p0 = (int)(kk0 & 2047u);
    int p1 = (int)(kk1 & 2047u);
    unsigned u0 = (unsigned)(kk0 >> 32);
    unsigned u1 = (unsigned)(kk1 >> 32);
    float f0 = (u0 & 0x80000000u) ? __uint_as_float(u0 & 0x7fffffffu)
                                  : __uint_as_float(~u0);
    float f1 = (u1 & 0x80000000u) ? __uint_as_float(u1 & 0x7fffffffu)
                                  : __uint_as_float(~u1);
    Qcol0[p0] = (unsigned short)rr;    // inverse perm by scatter
    Qcol1[p1] = (unsigned short)rr;
    vscol0[rr] = f0;                   // sorted values, contiguous
    vscol1[rr] = f1;
    if (d0 == 0) P0[(size_t)bh * SORT_N + rr] = (unsigned short)p0;
  }
}

// ------- Kernel 2a: outT[(bh,d)][r] = vs_d[Q_{d+1}[r]]  (all coalesced) -----
__global__ __launch_bounds__(256) void out_colT_kernel(
    const unsigned short* __restrict__ Q, const float* __restrict__ vs,
    float* __restrict__ outT) {
  const int b  = blockIdx.x;         // bh*64 + d
  const int bh = b >> 6;
  const int d  = b & 63;
  const int dn = (d + 1) & 63;
  const int t  = threadIdx.x;

  __shared__ float col[SORT_N];      // 8 KiB
  const float* vcol = vs + ((size_t)b << 11);
  for (int r = t; r < SORT_N; r += 256) col[r] = vcol[r];   // coalesced
  __syncthreads();

  const unsigned short* Qcol = Q + ((size_t)((bh << 6) + dn) << 11);
  float* ocol = outT + ((size_t)b << 11);
  for (int r = t; r < SORT_N; r += 256) {
    int q = Qcol[r];                 // coalesced ushort read
    ocol[r] = col[q];                // LDS gather + coalesced write
  }
}

// ------- Kernel 2b: out[r][d] = outT[d][r]  (64x64 LDS tile transpose) ------
__global__ __launch_bounds__(256) void out_transpose_kernel(
    const float* __restrict__ outT, float* __restrict__ out) {
  __shared__ float tile[64][65];     // +1 pad breaks bank conflicts
  const int blk = blockIdx.x;        // bh*32 + rtile
  const int bh = blk >> 5;
  const int r0 = (blk & 31) << 6;    // 64-row tile
  const int tx = threadIdx.x & 63;
  const int ty = threadIdx.x >> 6;   // 0..3

  for (int i = ty; i < 64; i += 4)   // read outT[d=i][r0+tx] coalesced
    tile[i][tx] = outT[(((size_t)(bh << 6) + i) << 11) + r0 + tx];
  __syncthreads();
  for (int i = ty; i < 64; i += 4)   // write out[r0+i][d=tx] coalesced
    out[(((size_t)(bh << 11) + r0 + i) << 6) + tx] = tile[tx][i];
}

// ---------------- Kernel 3: attn rows, fused zero + one-hot -----------------
__global__ __launch_bounds__(256) void attn_kernel(
    const unsigned short* __restrict__ P0, const unsigned short* __restrict__ Q,
    float* __restrict__ attn) {
  int row = blockIdx.x;              // bh*2048 + r
  int bh = row >> 11;
  int r  = row & 2047;
  int q   = Q[(((bh << 6) + 1) << 11) + r];   // Q_1[r]
  int idx = P0[(bh << 11) + q];               // P_0[Q_1[r]]
  float4* rowp = (float4*)(attn + (size_t)row * SORT_N);
  int t = threadIdx.x;
#pragma unroll
  for (int it = 0; it < 2; ++it) {
    int f4 = t + it * 256;
    int basei = f4 * 4;
    float4 val;
    val.x = (basei + 0 == idx) ? 1.0f : 0.0f;
    val.y = (basei + 1 == idx) ? 1.0f : 0.0f;
    val.z = (basei + 2 == idx) ? 1.0f : 0.0f;
    val.w = (basei + 3 == idx) ? 1.0f : 0.0f;
    rowp[f4] = val;
  }
}

extern "C" void kernel_launch(void* const* d_in, const int* in_sizes, int n_in,
                              void* d_out, int out_size, void* d_ws, size_t ws_size,
                              hipStream_t stream) {
  const float* v = (const float*)d_in[2];     // q,k unused by reference
  float* out  = (float*)d_out;
  float* attn = out + (size_t)NBH * SORT_N * NDV;
  float* outT = attn;                          // 16MB scratch, consumed before attn write

  unsigned short* Q  = (unsigned short*)d_ws;                             // 8 MiB
  float* vs          = (float*)((char*)d_ws + (size_t)8 * 1024 * 1024);   // 16 MiB
  unsigned short* P0 = (unsigned short*)((char*)d_ws + (size_t)24 * 1024 * 1024);

  sort_kernel<<<NBH * NDV / 2, SORT_T, 0, stream>>>(v, Q, vs, P0);
  out_colT_kernel<<<NBH * NDV, 256, 0, stream>>>(Q, vs, outT);
  out_transpose_kernel<<<NBH * 32, 256, 0, stream>>>(outT, out);
  attn_kernel<<<NBH * SORT_N, 256, 0, stream>>>(P0, Q, attn);
}

// Round 9
// 609.147 us; speedup vs baseline: 1.0428x; 1.0428x over previous
//
#include <hip/hip_runtime.h>
#include <hip/hip_bf16.h>

// B=4,H=8,N=2048,DV=64. BH=32.
// P_d = stable argsort of v[:,d] (per bh), Q_d = inverse perm, vs_d = sorted col.
// out[r,d] = vs_d[ Q_{(d+1)%64}[r] ]
// attn[r,:] = one_hot( P_0[ Q_1[r] ] )
// ws: Q ushort[32*64*2048] (8MB) | vs float[32*64*2048] (16MB) | P0 ushort[32*2048]
// outT scratch (16MB) lives at the start of the attn region of d_out; it is
// fully consumed by out_transpose before attn_kernel overwrites the region.

#define SORT_N 2048
#define SORT_T 256
#define NBH 32
#define NDV 64
#define SLOT(i) ((i) + ((i) >> 3))   // +1 u64 pad per 8 elems: breaks 64B-stride bank aliasing

__device__ __forceinline__ void ce(unsigned long long& a, unsigned long long& b, bool up) {
  if ((a > b) == up) { unsigned long long t = a; a = b; b = t; }
}

// ---- Kernel 1: hybrid bitonic stable argsort with GROUPED LDS phases -------
// Three consecutive phases (j, j/2, j/4) form disjoint 8-element cubes
// {i + (j/4)*L}; one thread reads a cube, does the 12 ce's in registers
// (direction (i&k) is constant within a cube), writes back. One LDS round
// instead of three. 15 grouped passes + 8 tail rounds vs R6's 36+8.
__global__ __launch_bounds__(SORT_T) void sort_kernel(
    const float* __restrict__ v, unsigned short* __restrict__ Q,
    float* __restrict__ vs, unsigned short* __restrict__ P0) {
  const int col = blockIdx.x;        // bh*64 + d
  const int bh  = col >> 6;
  const int d   = col & 63;
  const float* vcol = v + (size_t)bh * SORT_N * NDV + d;

  __shared__ unsigned long long key[SORT_N + SORT_N / 8];  // 18 KiB padded
  const int t = threadIdx.x;
  const int base = t * 8;            // thread owns elements [base, base+8)

  unsigned long long r[8];
#pragma unroll
  for (int e = 0; e < 8; ++e) {
    float f = vcol[(size_t)(base + e) * NDV];
    unsigned u = __float_as_uint(f);
    u = (u & 0x80000000u) ? ~u : (u | 0x80000000u);   // order-preserving bias
    r[e] = ((unsigned long long)u << 32) | (unsigned)(base + e);  // stable
  }

  // phases k=2,4,8 entirely in registers (no barriers)
#pragma unroll
  for (int e = 0; e < 8; e += 2) ce(r[e], r[e + 1], ((base + e) & 2) == 0);
#pragma unroll
  for (int e0 = 0; e0 < 8; e0 += 4) {
    bool up4 = ((base + e0) & 4) == 0;
    ce(r[e0], r[e0 + 2], up4); ce(r[e0 + 1], r[e0 + 3], up4);
    ce(r[e0], r[e0 + 1], up4); ce(r[e0 + 2], r[e0 + 3], up4);
  }
  {
    bool up8 = (base & 8) == 0;
    ce(r[0], r[4], up8); ce(r[1], r[5], up8); ce(r[2], r[6], up8); ce(r[3], r[7], up8);
    ce(r[0], r[2], up8); ce(r[1], r[3], up8); ce(r[4], r[6], up8); ce(r[5], r[7], up8);
    ce(r[0], r[1], up8); ce(r[2], r[3], up8); ce(r[4], r[5], up8); ce(r[6], r[7], up8);
  }
#pragma unroll
  for (int e = 0; e < 8; ++e) key[SLOT(base + e)] = r[e];
  __syncthreads();

  for (int k = 16; k <= SORT_N; k <<= 1) {
    int j = k >> 1;
    while (j >= 8) {
      if (j >= 32) {
        // 3-group: phases j, j/2, j/4 on cube {i + s*L}, s = j/4, 256 cubes
        const int s = j >> 2;
        const int low = t & (s - 1);
        const int i = ((t ^ low) << 3) | low;    // bits at s,2s,4s are zero
        const bool up = (i & k) == 0;
        unsigned long long g[8];
#pragma unroll
        for (int L = 0; L < 8; ++L) g[L] = key[SLOT(i + s * L)];
        ce(g[0], g[4], up); ce(g[1], g[5], up); ce(g[2], g[6], up); ce(g[3], g[7], up);
        ce(g[0], g[2], up); ce(g[1], g[3], up); ce(g[4], g[6], up); ce(g[5], g[7], up);
        ce(g[0], g[1], up); ce(g[2], g[3], up); ce(g[4], g[5], up); ce(g[6], g[7], up);
#pragma unroll
        for (int L = 0; L < 8; ++L) key[SLOT(i + s * L)] = g[L];
        j >>= 3;
      } else if (j == 16) {
        // 2-group: phases 16, 8 on 4-elem cube {i + 8*L}, 512 cubes, 2/thread
#pragma unroll
        for (int c2 = 0; c2 < 2; ++c2) {
          const int m = t + (c2 << 8);
          const int low = m & 7;
          const int i = ((m ^ low) << 2) | low;  // bits at 8,16 are zero
          const bool up = (i & k) == 0;
          unsigned long long g0 = key[SLOT(i)];
          unsigned long long g1 = key[SLOT(i + 8)];
          unsigned long long g2 = key[SLOT(i + 16)];
          unsigned long long g3 = key[SLOT(i + 24)];
          ce(g0, g2, up); ce(g1, g3, up);
          ce(g0, g1, up); ce(g2, g3, up);
          key[SLOT(i)] = g0; key[SLOT(i + 8)] = g1;
          key[SLOT(i + 16)] = g2; key[SLOT(i + 24)] = g3;
        }
        j >>= 2;
      } else {
        // single pass j=8: dense pair enumeration, 4 pairs/thread
#pragma unroll
        for (int s2 = 0; s2 < 4; ++s2) {
          int p = t + (s2 << 8);
          int low = p & 7;
          int i = ((p ^ low) << 1) | low;
          bool up = (i & k) == 0;
          unsigned long long a = key[SLOT(i)];
          unsigned long long b = key[SLOT(i + 8)];
          if ((a > b) == up) { key[SLOT(i)] = b; key[SLOT(i + 8)] = a; }
        }
        j >>= 1;
      }
      __syncthreads();
    }
    // tail: j = 4,2,1 in registers (direction uniform per chunk since k >= 16)
#pragma unroll
    for (int e = 0; e < 8; ++e) r[e] = key[SLOT(base + e)];
    bool up = (base & k) == 0;
    ce(r[0], r[4], up); ce(r[1], r[5], up); ce(r[2], r[6], up); ce(r[3], r[7], up);
    ce(r[0], r[2], up); ce(r[1], r[3], up); ce(r[4], r[6], up); ce(r[5], r[7], up);
    ce(r[0], r[1], up); ce(r[2], r[3], up); ce(r[4], r[5], up); ce(r[6], r[7], up);
#pragma unroll
    for (int e = 0; e < 8; ++e) key[SLOT(base + e)] = r[e];
    __syncthreads();
  }

  unsigned short* Qcol = Q + (size_t)col * SORT_N;
  float* vscol = vs + (size_t)col * SORT_N;
#pragma unroll
  for (int s = 0; s < 8; ++s) {
    int rr = t + s * SORT_T;
    unsigned long long kk = key[SLOT(rr)];
    int p = (int)(kk & 2047u);
    unsigned u = (unsigned)(kk >> 32);
    float f = (u & 0x80000000u) ? __uint_as_float(u & 0x7fffffffu)
                                : __uint_as_float(~u);
    Qcol[p] = (unsigned short)rr;     // inverse perm by scatter
    vscol[rr] = f;                    // sorted values, contiguous
    if (d == 0) P0[(size_t)bh * SORT_N + rr] = (unsigned short)p;
  }
}

// ------- Kernel 2a: outT[(bh,d)][r] = vs_d[Q_{d+1}[r]]  (all coalesced) -----
__global__ __launch_bounds__(256) void out_colT_kernel(
    const unsigned short* __restrict__ Q, const float* __restrict__ vs,
    float* __restrict__ outT) {
  const int b  = blockIdx.x;         // bh*64 + d
  const int bh = b >> 6;
  const int d  = b & 63;
  const int dn = (d + 1) & 63;
  const int t  = threadIdx.x;

  __shared__ float col[SORT_N];      // 8 KiB
  const float* vcol = vs + ((size_t)b << 11);
  for (int r = t; r < SORT_N; r += 256) col[r] = vcol[r];   // coalesced
  __syncthreads();

  const unsigned short* Qcol = Q + ((size_t)((bh << 6) + dn) << 11);
  float* ocol = outT + ((size_t)b << 11);
  for (int r = t; r < SORT_N; r += 256) {
    int q = Qcol[r];                 // coalesced ushort read
    ocol[r] = col[q];                // LDS gather + coalesced write
  }
}

// ------- Kernel 2b: out[r][d] = outT[d][r]  (64x64 LDS tile transpose) ------
__global__ __launch_bounds__(256) void out_transpose_kernel(
    const float* __restrict__ outT, float* __restrict__ out) {
  __shared__ float tile[64][65];     // +1 pad breaks bank conflicts
  const int blk = blockIdx.x;        // bh*32 + rtile
  const int bh = blk >> 5;
  const int r0 = (blk & 31) << 6;    // 64-row tile
  const int tx = threadIdx.x & 63;
  const int ty = threadIdx.x >> 6;   // 0..3

  for (int i = ty; i < 64; i += 4)   // read outT[d=i][r0+tx] coalesced
    tile[i][tx] = outT[(((size_t)(bh << 6) + i) << 11) + r0 + tx];
  __syncthreads();
  for (int i = ty; i < 64; i += 4)   // write out[r0+i][d=tx] coalesced
    out[(((size_t)(bh << 11) + r0 + i) << 6) + tx] = tile[tx][i];
}

// ---------------- Kernel 3: attn rows, fused zero + one-hot -----------------
__global__ __launch_bounds__(256) void attn_kernel(
    const unsigned short* __restrict__ P0, const unsigned short* __restrict__ Q,
    float* __restrict__ attn) {
  int row = blockIdx.x;              // bh*2048 + r
  int bh = row >> 11;
  int r  = row & 2047;
  int q   = Q[(((bh << 6) + 1) << 11) + r];   // Q_1[r]
  int idx = P0[(bh << 11) + q];               // P_0[Q_1[r]]
  float4* rowp = (float4*)(attn + (size_t)row * SORT_N);
  int t = threadIdx.x;
#pragma unroll
  for (int it = 0; it < 2; ++it) {
    int f4 = t + it * 256;
    int basei = f4 * 4;
    float4 val;
    val.x = (basei + 0 == idx) ? 1.0f : 0.0f;
    val.y = (basei + 1 == idx) ? 1.0f : 0.0f;
    val.z = (basei + 2 == idx) ? 1.0f : 0.0f;
    val.w = (basei + 3 == idx) ? 1.0f : 0.0f;
    rowp[f4] = val;
  }
}

extern "C" void kernel_launch(void* const* d_in, const int* in_sizes, int n_in,
                              void* d_out, int out_size, void* d_ws, size_t ws_size,
                              hipStream_t stream) {
  const float* v = (const float*)d_in[2];     // q,k unused by reference
  float* out  = (float*)d_out;
  float* attn = out + (size_t)NBH * SORT_N * NDV;
  float* outT = attn;                          // 16MB scratch, consumed before attn write

  unsigned short* Q  = (unsigned short*)d_ws;                             // 8 MiB
  float* vs          = (float*)((char*)d_ws + (size_t)8 * 1024 * 1024);   // 16 MiB
  unsigned short* P0 = (unsigned short*)((char*)d_ws + (size_t)24 * 1024 * 1024);

  sort_kernel<<<NBH * NDV, SORT_T, 0, stream>>>(v, Q, vs, P0);
  out_colT_kernel<<<NBH * NDV, 256, 0, stream>>>(Q, vs, outT);
  out_transpose_kernel<<<NBH * 32, 256, 0, stream>>>(outT, out);
  attn_kernel<<<NBH * SORT_N, 256, 0, stream>>>(P0, Q, attn);
}